// Round 1
// baseline (264.485 us; speedup 1.0000x reference)
//
#include <hip/hip_runtime.h>
#include <math.h>

#define BB 1024
#define TT 196
#define NQ 4
#define QDIM 16
#define NC 10

// ---------------- Kernel 1: quanvolution ----------------
// One thread per (b, t) patch. RY product state (real), U matvec (complex),
// signed-probability sums -> 4 <Z> values. Writes seq in (T, B, 4) layout.
__global__ void quanv_kernel(const float* __restrict__ x,
                             const float* __restrict__ U_re,
                             const float* __restrict__ U_im,
                             float* __restrict__ seq) {
    __shared__ float Ur[QDIM * QDIM];
    __shared__ float Ui[QDIM * QDIM];
    for (int i = threadIdx.x; i < QDIM * QDIM; i += blockDim.x) {
        Ur[i] = U_re[i];
        Ui[i] = U_im[i];
    }
    __syncthreads();

    int tid = blockIdx.x * blockDim.x + threadIdx.x;
    if (tid >= BB * TT) return;
    int b = tid / TT;
    int t = tid % TT;
    int r = t / 14, c = t % 14;
    const float* img = x + (size_t)b * 784;

    float ang[4];
    ang[0] = img[(2 * r) * 28 + 2 * c];
    ang[1] = img[(2 * r) * 28 + 2 * c + 1];
    ang[2] = img[(2 * r + 1) * 28 + 2 * c];
    ang[3] = img[(2 * r + 1) * 28 + 2 * c + 1];

    float cc[4], ss[4];
#pragma unroll
    for (int w = 0; w < 4; ++w) {
        float sv, cv;
        __sincosf(0.5f * ang[w], &sv, &cv);
        ss[w] = sv;
        cc[w] = cv;
    }

    // product-state amplitudes (real): index j bits (b0 b1 b2 b3), wire0 = MSB
    float a[16];
#pragma unroll
    for (int j = 0; j < 16; ++j) {
        float v = ((j >> 3) & 1) ? ss[0] : cc[0];
        v *= ((j >> 2) & 1) ? ss[1] : cc[1];
        v *= ((j >> 1) & 1) ? ss[2] : cc[2];
        v *= ((j >> 0) & 1) ? ss[3] : cc[3];
        a[j] = v;
    }

    float z0 = 0.f, z1 = 0.f, z2 = 0.f, z3 = 0.f;
#pragma unroll
    for (int j = 0; j < 16; ++j) {
        float vr = 0.f, vi = 0.f;
#pragma unroll
        for (int k = 0; k < 16; ++k) {
            vr = fmaf(Ur[j * 16 + k], a[k], vr);
            vi = fmaf(Ui[j * 16 + k], a[k], vi);
        }
        float p = vr * vr + vi * vi;
        z0 += ((j >> 3) & 1) ? -p : p;
        z1 += ((j >> 2) & 1) ? -p : p;
        z2 += ((j >> 1) & 1) ? -p : p;
        z3 += ((j >> 0) & 1) ? -p : p;
    }

    float4 out = make_float4(z0, z1, z2, z3);
    *reinterpret_cast<float4*>(seq + ((size_t)t * BB + b) * 4) = out;
}

// ---------------- Kernel 2: QLSTM + classifier ----------------
__device__ __forceinline__ float sigmoid_f(float v) {
    return 1.f / (1.f + __expf(-v));
}

__device__ __forceinline__ float tanh_fast(float v) {
    float av = fabsf(v);
    float e = __expf(-2.f * av);
    float t = (1.f - e) / (1.f + e);
    return copysignf(t, v);
}

// Closed-form qlayer: z_w from products of cos(angle_w).
// final measured bits: w0 = b1^b2^b3, w1 = b0^b1, w2 = b0^b1^b2, w3 = b0^b1^b2^b3
__device__ __forceinline__ void qgate(const float w[4][8], const float b2[4],
                                      const float comb[8], float z[4]) {
    float C[4];
#pragma unroll
    for (int q = 0; q < 4; ++q) {
        float ang = b2[q];
#pragma unroll
        for (int j = 0; j < 8; ++j) ang = fmaf(w[q][j], comb[j], ang);
        C[q] = __cosf(ang);
    }
    z[1] = C[0] * C[1];
    z[2] = z[1] * C[2];
    z[3] = z[2] * C[3];
    z[0] = C[1] * C[2] * C[3];
}

__global__ void qlstm_kernel(const float* __restrict__ seq,
                             const float* __restrict__ Wf, const float* __restrict__ bf,
                             const float* __restrict__ Wi, const float* __restrict__ bi,
                             const float* __restrict__ Wg, const float* __restrict__ bg,
                             const float* __restrict__ Wo, const float* __restrict__ bo,
                             const float* __restrict__ rxf, const float* __restrict__ rxi,
                             const float* __restrict__ rxg, const float* __restrict__ rxo,
                             const float* __restrict__ Wc, const float* __restrict__ bc,
                             float* __restrict__ out) {
    int b = blockIdx.x * blockDim.x + threadIdx.x;
    if (b >= BB) return;

    float wf[4][8], wi[4][8], wg[4][8], wo[4][8];
    float b2f[4], b2i[4], b2g[4], b2o[4];
#pragma unroll
    for (int q = 0; q < 4; ++q) {
#pragma unroll
        for (int j = 0; j < 8; ++j) {
            wf[q][j] = Wf[q * 8 + j];
            wi[q][j] = Wi[q * 8 + j];
            wg[q][j] = Wg[q * 8 + j];
            wo[q][j] = Wo[q * 8 + j];
        }
        b2f[q] = bf[q] + rxf[q];
        b2i[q] = bi[q] + rxi[q];
        b2g[q] = bg[q] + rxg[q];
        b2o[q] = bo[q] + rxo[q];
    }

    float h[4] = {0.f, 0.f, 0.f, 0.f};
    float cs[4] = {0.f, 0.f, 0.f, 0.f};

    for (int t = 0; t < TT; ++t) {
        float4 xt = *reinterpret_cast<const float4*>(seq + ((size_t)t * BB + b) * 4);
        float comb[8] = {xt.x, xt.y, xt.z, xt.w, h[0], h[1], h[2], h[3]};
        float zf[4], zi[4], zg[4], zo[4];
        qgate(wf, b2f, comb, zf);
        qgate(wi, b2i, comb, zi);
        qgate(wg, b2g, comb, zg);
        qgate(wo, b2o, comb, zo);
#pragma unroll
        for (int q = 0; q < 4; ++q) {
            float fv = sigmoid_f(zf[q]);
            float iv = sigmoid_f(zi[q]);
            float gv = tanh_fast(zg[q]);
            float ov = sigmoid_f(zo[q]);
            cs[q] = fmaf(fv, cs[q], iv * gv);
            h[q] = ov * tanh_fast(cs[q]);
        }
    }

    // classifier + log_softmax
    float l[NC];
    float mx = -1e30f;
#pragma unroll
    for (int k = 0; k < NC; ++k) {
        float v = bc[k];
#pragma unroll
        for (int q = 0; q < 4; ++q) v = fmaf(Wc[k * 4 + q], h[q], v);
        l[k] = v;
        mx = fmaxf(mx, v);
    }
    float se = 0.f;
#pragma unroll
    for (int k = 0; k < NC; ++k) se += __expf(l[k] - mx);
    float lse = mx + __logf(se);
#pragma unroll
    for (int k = 0; k < NC; ++k) out[(size_t)b * NC + k] = l[k] - lse;
}

extern "C" void kernel_launch(void* const* d_in, const int* in_sizes, int n_in,
                              void* d_out, int out_size, void* d_ws, size_t ws_size,
                              hipStream_t stream) {
    (void)in_sizes; (void)n_in; (void)out_size; (void)ws_size;
    const float* x    = (const float*)d_in[0];
    const float* U_re = (const float*)d_in[1];
    const float* U_im = (const float*)d_in[2];
    const float* Wf   = (const float*)d_in[3];
    const float* bf   = (const float*)d_in[4];
    const float* Wi   = (const float*)d_in[5];
    const float* bi   = (const float*)d_in[6];
    const float* Wg   = (const float*)d_in[7];
    const float* bg   = (const float*)d_in[8];
    const float* Wo   = (const float*)d_in[9];
    const float* bo   = (const float*)d_in[10];
    const float* rxf  = (const float*)d_in[11];
    const float* rxi  = (const float*)d_in[12];
    const float* rxg  = (const float*)d_in[13];
    const float* rxo  = (const float*)d_in[14];
    const float* Wc   = (const float*)d_in[15];
    const float* bc   = (const float*)d_in[16];

    float* seq = (float*)d_ws;              // (T, B, 4) = 3.2 MB
    float* out = (float*)d_out;             // (B, 10)

    quanv_kernel<<<(BB * TT + 255) / 256, 256, 0, stream>>>(x, U_re, U_im, seq);
    qlstm_kernel<<<BB / 64, 64, 0, stream>>>(seq, Wf, bf, Wi, bi, Wg, bg, Wo, bo,
                                             rxf, rxi, rxg, rxo, Wc, bc, out);
}

// Round 2
// 76.489 us; speedup vs baseline: 3.4578x; 3.4578x over previous
//
#include <hip/hip_runtime.h>
#include <math.h>

#define BB 1024
#define TT 196
#define QDIM 16
#define NC 10

// ---------------- Kernel 1: quanvolution ----------------
// One thread per (b, t) patch. RY product state (real), U matvec (complex),
// signed-probability sums -> 4 <Z> values. Writes seq in (T, B, 4) layout.
__global__ void quanv_kernel(const float* __restrict__ x,
                             const float* __restrict__ U_re,
                             const float* __restrict__ U_im,
                             float* __restrict__ seq) {
    __shared__ float Ur[QDIM * QDIM];
    __shared__ float Ui[QDIM * QDIM];
    for (int i = threadIdx.x; i < QDIM * QDIM; i += blockDim.x) {
        Ur[i] = U_re[i];
        Ui[i] = U_im[i];
    }
    __syncthreads();

    int tid = blockIdx.x * blockDim.x + threadIdx.x;
    if (tid >= BB * TT) return;
    int b = tid / TT;
    int t = tid % TT;
    int r = t / 14, c = t % 14;
    const float* img = x + (size_t)b * 784;

    float ang[4];
    ang[0] = img[(2 * r) * 28 + 2 * c];
    ang[1] = img[(2 * r) * 28 + 2 * c + 1];
    ang[2] = img[(2 * r + 1) * 28 + 2 * c];
    ang[3] = img[(2 * r + 1) * 28 + 2 * c + 1];

    float cc[4], ss[4];
#pragma unroll
    for (int w = 0; w < 4; ++w) {
        float sv, cv;
        __sincosf(0.5f * ang[w], &sv, &cv);
        ss[w] = sv;
        cc[w] = cv;
    }

    // product-state amplitudes (real): index j bits (b0 b1 b2 b3), wire0 = MSB
    float a[16];
#pragma unroll
    for (int j = 0; j < 16; ++j) {
        float v = ((j >> 3) & 1) ? ss[0] : cc[0];
        v *= ((j >> 2) & 1) ? ss[1] : cc[1];
        v *= ((j >> 1) & 1) ? ss[2] : cc[2];
        v *= ((j >> 0) & 1) ? ss[3] : cc[3];
        a[j] = v;
    }

    float z0 = 0.f, z1 = 0.f, z2 = 0.f, z3 = 0.f;
#pragma unroll
    for (int j = 0; j < 16; ++j) {
        float vr = 0.f, vi = 0.f;
#pragma unroll
        for (int k = 0; k < 16; ++k) {
            vr = fmaf(Ur[j * 16 + k], a[k], vr);
            vi = fmaf(Ui[j * 16 + k], a[k], vi);
        }
        float p = vr * vr + vi * vi;
        z0 += ((j >> 3) & 1) ? -p : p;
        z1 += ((j >> 2) & 1) ? -p : p;
        z2 += ((j >> 1) & 1) ? -p : p;
        z3 += ((j >> 0) & 1) ? -p : p;
    }

    float4 out = make_float4(z0, z1, z2, z3);
    *reinterpret_cast<float4*>(seq + ((size_t)t * BB + b) * 4) = out;
}

// ---------------- Kernel 2: QLSTM, 4 lanes per batch element ----------------
// lane g in quad owns gate g (0=f,1=i,2=g,3=o). All weights in named regs.
// Cross-gate mixing via quad_perm DPP only (VALU latency, no LDS).

// quad_perm DPP helper. CTRL byte: sel0 | sel1<<2 | sel2<<4 | sel3<<6
template <int CTRL>
__device__ __forceinline__ float qp(float v) {
    return __int_as_float(__builtin_amdgcn_update_dpp(
        0, __float_as_int(v), CTRL, 0xF, 0xF, true));
}
#define QP_XOR3 0x1B  // [3,2,1,0]
#define QP_XOR1 0xB1  // [1,0,3,2]
#define QP_BC0  0x00  // [0,0,0,0]

__device__ __forceinline__ float rcp_f(float v) {
    return __builtin_amdgcn_rcpf(v);
}

__global__ __launch_bounds__(64) void qlstm4_kernel(
    const float* __restrict__ seq,
    const float* __restrict__ Wf, const float* __restrict__ bf,
    const float* __restrict__ Wi, const float* __restrict__ bi,
    const float* __restrict__ Wg, const float* __restrict__ bg,
    const float* __restrict__ Wo, const float* __restrict__ bo,
    const float* __restrict__ rxf, const float* __restrict__ rxi,
    const float* __restrict__ rxg, const float* __restrict__ rxo,
    const float* __restrict__ Wc, const float* __restrict__ bc,
    float* __restrict__ out) {
    int tid = blockIdx.x * 64 + threadIdx.x;
    int b = tid >> 2;
    int g = tid & 3;
    if (b >= BB) return;

    const float* W;
    const float* bb;
    const float* rx;
    if (g == 0)      { W = Wf; bb = bf; rx = rxf; }
    else if (g == 1) { W = Wi; bb = bi; rx = rxi; }
    else if (g == 2) { W = Wg; bb = bg; rx = rxg; }
    else             { W = Wo; bb = bo; rx = rxo; }

    // this lane's gate weights: x-part, h-part, bias+rx  (all static regs)
    float wx[4][4], wh[4][4], pre[4];
#pragma unroll
    for (int q = 0; q < 4; ++q) {
#pragma unroll
        for (int j = 0; j < 4; ++j) {
            wx[q][j] = W[q * 8 + j];
            wh[q][j] = W[q * 8 + 4 + j];
        }
        pre[q] = bb[q] + rx[q];
    }
    // lane-uniform nonlinearity constants: sigmoid for f,i,o; tanh=2*sig(2x)-1 for g
    const float m1 = (g == 2) ? 2.f : 1.f;
    const float m2 = m1;
    const float a2 = (g == 2) ? -1.f : 0.f;

    float h[4] = {0.f, 0.f, 0.f, 0.f};
    float c[4] = {0.f, 0.f, 0.f, 0.f};

    float4 nxt = *reinterpret_cast<const float4*>(seq + (size_t)b * 4);  // t=0
    for (int t = 0; t < TT; ++t) {
        float4 xt = nxt;
        int tn = (t + 1 < TT) ? (t + 1) : (TT - 1);
        nxt = *reinterpret_cast<const float4*>(seq + ((size_t)tn * BB + b) * 4);

        // 4 angles for this lane's gate
        float C[4];
#pragma unroll
        for (int q = 0; q < 4; ++q) {
            float ang = pre[q];
            ang = fmaf(wx[q][0], xt.x, ang);
            ang = fmaf(wx[q][1], xt.y, ang);
            ang = fmaf(wx[q][2], xt.z, ang);
            ang = fmaf(wx[q][3], xt.w, ang);
            ang = fmaf(wh[q][0], h[0], ang);
            ang = fmaf(wh[q][1], h[1], ang);
            ang = fmaf(wh[q][2], h[2], ang);
            ang = fmaf(wh[q][3], h[3], ang);
            C[q] = __cosf(ang);
        }
        // closed-form <Z>: z0=C1C2C3, z1=C0C1, z2=C0C1C2, z3=C0C1C2C3
        float z[4];
        z[1] = C[0] * C[1];
        z[2] = z[1] * C[2];
        z[3] = z[2] * C[3];
        z[0] = C[1] * (C[2] * C[3]);

        // gate nonlinearity (lane-uniform constants, no divergence)
        float val[4];
#pragma unroll
        for (int q = 0; q < 4; ++q) {
            float e = __expf(-z[q] * m1);
            float s = rcp_f(1.f + e);
            val[q] = fmaf(s, m2, a2);
        }

        // cross-gate combine within quad: lanes {f,i,g,o}
#pragma unroll
        for (int q = 0; q < 4; ++q) {
            float s1 = qp<QP_XOR3>(val[q]);   // lane0<-o, lane1<-g, lane2<-i, lane3<-f
            float u  = val[q] * s1;           // lane1 = i*g
            float s2 = qp<QP_XOR1>(u);        // lane0 <- i*g
            c[q] = fmaf(val[q], c[q], s2);    // lane0: f*c + i*g (others junk, unused)
            float e2 = __expf(-2.f * c[q]);
            float th = fmaf(2.f, rcp_f(1.f + e2), -1.f);  // tanh(c), overflow-safe
            float hq = s1 * th;               // lane0: o * tanh(c)
            h[q] = qp<QP_BC0>(hq);            // broadcast lane0 -> quad
        }
    }

    // classifier + log_softmax (lane 0 of each quad)
    if (g == 0) {
        float l[NC];
        float mx = -1e30f;
#pragma unroll
        for (int k = 0; k < NC; ++k) {
            float v = bc[k];
#pragma unroll
            for (int q = 0; q < 4; ++q) v = fmaf(Wc[k * 4 + q], h[q], v);
            l[k] = v;
            mx = fmaxf(mx, v);
        }
        float se = 0.f;
#pragma unroll
        for (int k = 0; k < NC; ++k) se += __expf(l[k] - mx);
        float lse = mx + __logf(se);
#pragma unroll
        for (int k = 0; k < NC; ++k) out[(size_t)b * NC + k] = l[k] - lse;
    }
}

extern "C" void kernel_launch(void* const* d_in, const int* in_sizes, int n_in,
                              void* d_out, int out_size, void* d_ws, size_t ws_size,
                              hipStream_t stream) {
    (void)in_sizes; (void)n_in; (void)out_size; (void)ws_size;
    const float* x    = (const float*)d_in[0];
    const float* U_re = (const float*)d_in[1];
    const float* U_im = (const float*)d_in[2];
    const float* Wf   = (const float*)d_in[3];
    const float* bf   = (const float*)d_in[4];
    const float* Wi   = (const float*)d_in[5];
    const float* bi   = (const float*)d_in[6];
    const float* Wg   = (const float*)d_in[7];
    const float* bg   = (const float*)d_in[8];
    const float* Wo   = (const float*)d_in[9];
    const float* bo   = (const float*)d_in[10];
    const float* rxf  = (const float*)d_in[11];
    const float* rxi  = (const float*)d_in[12];
    const float* rxg  = (const float*)d_in[13];
    const float* rxo  = (const float*)d_in[14];
    const float* Wc   = (const float*)d_in[15];
    const float* bc   = (const float*)d_in[16];

    float* seq = (float*)d_ws;   // (T, B, 4) = 3.2 MB
    float* out = (float*)d_out;  // (B, 10)

    quanv_kernel<<<(BB * TT + 255) / 256, 256, 0, stream>>>(x, U_re, U_im, seq);
    qlstm4_kernel<<<(BB * 4) / 64, 64, 0, stream>>>(seq, Wf, bf, Wi, bi, Wg, bg,
                                                    Wo, bo, rxf, rxi, rxg, rxo,
                                                    Wc, bc, out);
}